// Round 1
// baseline (443.360 us; speedup 1.0000x reference)
//
#include <hip/hip_runtime.h>
#include <hip/hip_bf16.h>

typedef __attribute__((ext_vector_type(8))) short bf16x8;   // 8 bf16 (4 VGPRs)
typedef __attribute__((ext_vector_type(8))) short short8v;
typedef __attribute__((ext_vector_type(4))) float f32x4;
typedef __attribute__((ext_vector_type(4))) unsigned short ushort4v;

__device__ __forceinline__ float bf_bits_to_f(short s) {
  unsigned int u = ((unsigned int)(unsigned short)s) << 16;
  union { unsigned int u; float f; } c; c.u = u; return c.f;
}
// round-to-nearest-even fp32 -> bf16 bits (finite inputs)
__device__ __forceinline__ unsigned short f_to_bf_bits(float f) {
  union { float f; unsigned int u; } c; c.f = f;
  unsigned int r = c.u + 0x7FFFu + ((c.u >> 16) & 1u);
  return (unsigned short)(r >> 16);
}

// ---------------- fp32 -> bf16 convert (vectorized, grid-stride) ----------------
__global__ __launch_bounds__(256) void cvt_bf16_kernel(const float* __restrict__ in,
                                                       unsigned short* __restrict__ out,
                                                       long n) {
  const long nchunks = n >> 2;
  const long stride = (long)gridDim.x * 256;
  for (long c = (long)blockIdx.x * 256 + threadIdx.x; c < nchunks; c += stride) {
    f32x4 v = *(const f32x4*)(in + c * 4);
    ushort4v o;
    o[0] = f_to_bf_bits(v[0]); o[1] = f_to_bf_bits(v[1]);
    o[2] = f_to_bf_bits(v[2]); o[3] = f_to_bf_bits(v[3]);
    *(ushort4v*)(out + c * 4) = o;
  }
}

// ---------------- W [K][N] fp32 -> Wt [N][K] bf16 (512x512 each) ----------------
__global__ __launch_bounds__(256) void transpose_w_kernel(
    const float* __restrict__ W0, const float* __restrict__ W1, const float* __restrict__ W2,
    unsigned short* __restrict__ T0, unsigned short* __restrict__ T1, unsigned short* __restrict__ T2) {
  const float* W = (blockIdx.z == 0) ? W0 : (blockIdx.z == 1) ? W1 : W2;
  unsigned short* T = (blockIdx.z == 0) ? T0 : (blockIdx.z == 1) ? T1 : T2;
  __shared__ float t[32][33];
  const int tx = threadIdx.x & 31, ty = threadIdx.x >> 5;  // 32 x 8
  const int n0 = blockIdx.x * 32, k0 = blockIdx.y * 32;
#pragma unroll
  for (int j = 0; j < 4; ++j)
    t[ty + 8 * j][tx] = W[(long)(k0 + ty + 8 * j) * 512 + n0 + tx];
  __syncthreads();
#pragma unroll
  for (int j = 0; j < 4; ++j)
    T[(long)(n0 + ty + 8 * j) * 512 + k0 + tx] = f_to_bf_bits(t[tx][ty + 8 * j]);
}

// ---------------- bf16 GEMM: C[M][N] = A[M][K] * BT[N][K]^T * scale (+bias) ----------------
// 128x128 tile, 4 waves (each 64x64), 16x16x32 bf16 MFMA, global_load_lds staging.
template <bool BIAS, bool TRANSOUT, bool OUTBF16>
__global__ __launch_bounds__(256) void gemm_kernel(
    const unsigned short* __restrict__ A,   // [M][K] bf16 bits, per batch
    const unsigned short* __restrict__ BT,  // [N][K] bf16 bits, per batch
    const float* __restrict__ bias,         // [N] fp32 or null
    void* __restrict__ Cout,
    const int K, const float scale,
    const long strideA, const long strideBT, const long strideC, const int ldc) {
  __shared__ unsigned short lds[8192];  // A tile [128][32] then B tile [128][32]
  const int tid = threadIdx.x;
  const int lane = tid & 63;
  const int wv = tid >> 6;          // 0..3
  const int wr = wv >> 1, wc = wv & 1;
  const int z = blockIdx.z;
  const unsigned short* Ab = A + (long)z * strideA + (long)blockIdx.y * 128 * K;
  const unsigned short* Bb = BT + (long)z * strideBT + (long)blockIdx.x * 128 * K;

  f32x4 acc[4][4];
#pragma unroll
  for (int m = 0; m < 4; ++m)
#pragma unroll
    for (int n = 0; n < 4; ++n) acc[m][n] = (f32x4){0.f, 0.f, 0.f, 0.f};

  const int r15 = lane & 15, g = lane >> 4;
  const int kiters = K >> 5;

  for (int kt = 0; kt < kiters; ++kt) {
    // stage A and B tiles: 8KB each = 8 chunks of 1KB; chunk c = i*4 + wave
#pragma unroll
    for (int i = 0; i < 2; ++i) {
      const int c = i * 4 + wv;
      const int boff = c * 1024 + lane * 16;  // byte offset within 8KB tile
      const int row = boff >> 6;              // tile row (64B per row)
      const int colb = boff & 63;             // byte within row
      const char* srcA = (const char*)Ab + (long)row * (K * 2) + kt * 64 + colb;
      const char* srcB = (const char*)Bb + (long)row * (K * 2) + kt * 64 + colb;
      __builtin_amdgcn_global_load_lds(
          (const __attribute__((address_space(1))) void*)srcA,
          (__attribute__((address_space(3))) void*)(lds + c * 512), 16, 0, 0);
      __builtin_amdgcn_global_load_lds(
          (const __attribute__((address_space(1))) void*)srcB,
          (__attribute__((address_space(3))) void*)(lds + 4096 + c * 512), 16, 0, 0);
    }
    __syncthreads();  // drains vmcnt (compiler-inserted) + barrier

    bf16x8 af[4], bf[4];
#pragma unroll
    for (int m = 0; m < 4; ++m)
      af[m] = *(const bf16x8*)&lds[(wr * 64 + m * 16 + r15) * 32 + g * 8];
#pragma unroll
    for (int n = 0; n < 4; ++n)
      bf[n] = *(const bf16x8*)&lds[4096 + (wc * 64 + n * 16 + r15) * 32 + g * 8];
#pragma unroll
    for (int m = 0; m < 4; ++m)
#pragma unroll
      for (int n = 0; n < 4; ++n)
        acc[m][n] = __builtin_amdgcn_mfma_f32_16x16x32_bf16(af[m], bf[n], acc[m][n], 0, 0, 0);
    __syncthreads();  // protect LDS before next stage
  }

  // epilogue: C/D layout col = lane&15, row = (lane>>4)*4 + j
  const long crow0 = (long)blockIdx.y * 128 + wr * 64;
  const long ccol0 = (long)blockIdx.x * 128 + wc * 64;
#pragma unroll
  for (int n = 0; n < 4; ++n) {
    const long col = ccol0 + n * 16 + r15;
    const float bv = BIAS ? bias[col] : 0.f;
#pragma unroll
    for (int m = 0; m < 4; ++m) {
      const f32x4 v = acc[m][n];
#pragma unroll
      for (int j = 0; j < 4; ++j) {
        const long row = crow0 + m * 16 + g * 4 + j;
        const float val = v[j] * scale + bv;
        const long idx = TRANSOUT ? (col * (long)ldc + row) : (row * (long)ldc + col);
        if (OUTBF16)
          ((unsigned short*)Cout + (long)z * strideC)[idx] = f_to_bf_bits(val);
        else
          ((float*)Cout + (long)z * strideC)[idx] = val;
      }
    }
  }
}

// ---------------- in-place row softmax on bf16 scores, wave per row (1024 cols) ----------------
__global__ __launch_bounds__(256) void softmax_kernel(unsigned short* __restrict__ S) {
  const long row = (long)blockIdx.x * 4 + (threadIdx.x >> 6);
  const int lane = threadIdx.x & 63;
  unsigned short* p = S + row * 1024 + lane * 16;
  short8v a = *(const short8v*)p;
  short8v b = *(const short8v*)(p + 8);
  float f[16];
#pragma unroll
  for (int i = 0; i < 8; ++i) { f[i] = bf_bits_to_f(a[i]); f[8 + i] = bf_bits_to_f(b[i]); }
  float mx = f[0];
#pragma unroll
  for (int i = 1; i < 16; ++i) mx = fmaxf(mx, f[i]);
  for (int off = 1; off < 64; off <<= 1) mx = fmaxf(mx, __shfl_xor(mx, off));
  float sum = 0.f;
#pragma unroll
  for (int i = 0; i < 16; ++i) { f[i] = __expf(f[i] - mx); sum += f[i]; }
  for (int off = 1; off < 64; off <<= 1) sum += __shfl_xor(sum, off);
  const float inv = 1.f / sum;
  short8v oa, ob;
#pragma unroll
  for (int i = 0; i < 8; ++i) {
    oa[i] = (short)f_to_bf_bits(f[i] * inv);
    ob[i] = (short)f_to_bf_bits(f[8 + i] * inv);
  }
  *(short8v*)p = oa;
  *(short8v*)(p + 8) = ob;
}

extern "C" void kernel_launch(void* const* d_in, const int* in_sizes, int n_in,
                              void* d_out, int out_size, void* d_ws, size_t ws_size,
                              hipStream_t stream) {
  (void)in_sizes; (void)n_in; (void)out_size; (void)ws_size;
  const float* x     = (const float*)d_in[0];  // [16][4096][512]
  const float* audio = (const float*)d_in[1];  // [16][1024][512]
  const float* Wq    = (const float*)d_in[2];  // [512][512]
  const float* bq    = (const float*)d_in[3];
  const float* Wk    = (const float*)d_in[4];
  const float* bk    = (const float*)d_in[5];
  const float* Wv    = (const float*)d_in[6];
  const float* bv    = (const float*)d_in[7];
  float* out = (float*)d_out;                  // [16][4096][512] fp32

  // workspace carve (all sizes 256B-aligned naturally)
  char* ws = (char*)d_ws;
  size_t off = 0;
  auto carve = [&](size_t bytes) { char* p = ws + off; off += (bytes + 255) & ~(size_t)255; return p; };
  unsigned short* xb  = (unsigned short*)carve((size_t)65536 * 512 * 2);  // x bf16
  unsigned short* ab  = (unsigned short*)carve((size_t)16384 * 512 * 2);  // audio bf16
  unsigned short* wqt = (unsigned short*)carve((size_t)512 * 512 * 2);    // Wq^T bf16
  unsigned short* wkt = (unsigned short*)carve((size_t)512 * 512 * 2);
  unsigned short* wvt = (unsigned short*)carve((size_t)512 * 512 * 2);
  unsigned short* Qb  = (unsigned short*)carve((size_t)65536 * 512 * 2);  // Q bf16 [B*HW][512]
  unsigned short* Kb  = (unsigned short*)carve((size_t)16384 * 512 * 2);  // K bf16 [B*S][512]
  unsigned short* Vt  = (unsigned short*)carve((size_t)16384 * 512 * 2);  // V^T bf16 [B][512][1024]
  unsigned short* Sb  = (unsigned short*)carve((size_t)65536 * 1024 * 2); // scores/attn bf16 [B][4096][1024]

  // 1) converts
  cvt_bf16_kernel<<<2048, 256, 0, stream>>>(x, xb, (long)65536 * 512);
  cvt_bf16_kernel<<<1024, 256, 0, stream>>>(audio, ab, (long)16384 * 512);
  // 2) weight transposes
  transpose_w_kernel<<<dim3(16, 16, 3), 256, 0, stream>>>(Wq, Wk, Wv, wqt, wkt, wvt);
  // 3) projections (bf16 MFMA, fp32 acc, +bias, bf16 out)
  gemm_kernel<true, false, true><<<dim3(4, 512, 1), 256, 0, stream>>>(
      xb, wqt, bq, Qb, 512, 1.f, 0, 0, 0, 512);
  gemm_kernel<true, false, true><<<dim3(4, 128, 1), 256, 0, stream>>>(
      ab, wkt, bk, Kb, 512, 1.f, 0, 0, 0, 512);
  // V projection written transposed per batch: Vt[b][d][s]
  gemm_kernel<true, true, true><<<dim3(4, 8, 16), 256, 0, stream>>>(
      ab, wvt, bv, Vt, 512, 1.f, (long)1024 * 512, 0, (long)512 * 1024, 1024);
  // 4) scores = Q K^T * (1/sqrt(512)), bf16 out
  gemm_kernel<false, false, true><<<dim3(8, 32, 16), 256, 0, stream>>>(
      Qb, Kb, nullptr, Sb, 512, 0.044194173824159216f,
      (long)4096 * 512, (long)1024 * 512, (long)4096 * 1024, 1024);
  // 5) softmax in place (fp32 math)
  softmax_kernel<<<16384, 256, 0, stream>>>(Sb);
  // 6) out = P V  (fp32 out)
  gemm_kernel<false, false, false><<<dim3(4, 32, 16), 256, 0, stream>>>(
      Sb, Vt, nullptr, out, 1024, 1.f,
      (long)4096 * 1024, (long)512 * 1024, (long)4096 * 512, 512);
}